// Round 1
// baseline (7092.304 us; speedup 1.0000x reference)
//
#include <hip/hip_runtime.h>

// GPT forward, MI355X. f32 inputs; bf16 MFMA GEMMs with f32 accum;
// LN/softmax/residual kept in f32.

#define T_SEQ 1024
#define E_DIM 1024
#define H_NUM 16
#define D_HEAD 64
#define L_NUM 6
#define FF_DIM 4096
#define B_NUM 2
#define M_ROWS 2048   // B*T

using bf16x8 = __attribute__((ext_vector_type(8))) __bf16;
using f32x4  = __attribute__((ext_vector_type(4))) float;

__device__ __forceinline__ unsigned short f2bf(float f) {
  unsigned int u = __float_as_uint(f);
  u += 0x7fffu + ((u >> 16) & 1u);   // RNE
  return (unsigned short)(u >> 16);
}

// ---------------- embed: x[b*T+t][e] = tok_w[idx][e] + pos[t][e] ----------
__global__ __launch_bounds__(256) void embed_k(const int* __restrict__ idx,
                                               const float* __restrict__ tok_w,
                                               const float* __restrict__ pos,
                                               float* __restrict__ x) {
  const int i = blockIdx.x;            // 0..2047
  const int t = i & (T_SEQ - 1);
  const int tok = idx[i];
  const float4 a = ((const float4*)(tok_w + (size_t)tok * E_DIM))[threadIdx.x];
  const float4 p = ((const float4*)(pos + (size_t)t * E_DIM))[threadIdx.x];
  float4 o;
  o.x = a.x + p.x; o.y = a.y + p.y; o.z = a.z + p.z; o.w = a.w + p.w;
  ((float4*)(x + (size_t)i * E_DIM))[threadIdx.x] = o;
}

// ---------------- layernorm: f32 in -> bf16 out ---------------------------
__global__ __launch_bounds__(256) void ln_k(const float* __restrict__ x,
                                            const float* __restrict__ s,
                                            const float* __restrict__ b,
                                            unsigned short* __restrict__ out) {
  const int row = blockIdx.x, tid = threadIdx.x;
  const float4 v = ((const float4*)(x + (size_t)row * E_DIM))[tid];
  float sum = v.x + v.y + v.z + v.w;
  float sq  = v.x * v.x + v.y * v.y + v.z * v.z + v.w * v.w;
  #pragma unroll
  for (int off = 32; off; off >>= 1) {
    sum += __shfl_down(sum, off);
    sq  += __shfl_down(sq, off);
  }
  __shared__ float sm[10];
  const int wave = tid >> 6, lane = tid & 63;
  if (lane == 0) { sm[wave] = sum; sm[4 + wave] = sq; }
  __syncthreads();
  if (tid == 0) {
    const float ts = sm[0] + sm[1] + sm[2] + sm[3];
    const float tq = sm[4] + sm[5] + sm[6] + sm[7];
    const float mean = ts * (1.0f / E_DIM);
    const float var = tq * (1.0f / E_DIM) - mean * mean;
    sm[8] = mean;
    sm[9] = 1.0f / sqrtf(var + 1e-5f);
  }
  __syncthreads();
  const float mean = sm[8], inv = sm[9];
  const float4 sv = ((const float4*)s)[tid];
  const float4 bv = ((const float4*)b)[tid];
  ushort4 o;
  o.x = f2bf((v.x - mean) * inv * sv.x + bv.x);
  o.y = f2bf((v.y - mean) * inv * sv.y + bv.y);
  o.z = f2bf((v.z - mean) * inv * sv.z + bv.z);
  o.w = f2bf((v.w - mean) * inv * sv.w + bv.w);
  *(ushort4*)(out + (size_t)row * E_DIM + (tid << 2)) = o;
}

// ---------------- transpose + f32->bf16: WT[n][k] = W[k][n] ---------------
__global__ __launch_bounds__(256) void transpose_k(const float* __restrict__ W,
                                                   unsigned short* __restrict__ WT,
                                                   int K, int ldw) {
  __shared__ float tile[32][33];
  const int n0 = blockIdx.x << 5, k0 = blockIdx.y << 5;
  const int tx = threadIdx.x & 31, ty = threadIdx.x >> 5;
  #pragma unroll
  for (int i = ty; i < 32; i += 8)
    tile[i][tx] = W[(size_t)(k0 + i) * ldw + n0 + tx];
  __syncthreads();
  #pragma unroll
  for (int i = ty; i < 32; i += 8)
    WT[(size_t)(n0 + i) * K + k0 + tx] = f2bf(tile[tx][i]);
}

// ---------------- bf16 MFMA GEMM: C[M,N] = A[M,K] @ WT[N,K]^T -------------
// 128x128 tile, BK=32, 4 waves, 16x16x32_bf16, 4x4 frags per wave.
template<bool RELU, bool BIAS, bool RES, bool OBF16>
__global__ __launch_bounds__(256) void gemm_k(const unsigned short* __restrict__ A,
                                              const unsigned short* __restrict__ WT,
                                              const float* __restrict__ bias,
                                              const float* __restrict__ res,
                                              void* __restrict__ Cout,
                                              int ldc, int K) {
  __shared__ __align__(16) unsigned short As[128][32];
  __shared__ __align__(16) unsigned short Bs[128][32];
  const int tid = threadIdx.x;
  const int row0 = blockIdx.y << 7, col0 = blockIdx.x << 7;
  const int wave = tid >> 6, lane = tid & 63;
  const int wm = (wave >> 1) << 6, wn = (wave & 1) << 6;
  const int lr = lane & 15, lk = (lane >> 4) << 3;
  f32x4 acc[4][4] = {};
  for (int k0 = 0; k0 < K; k0 += 32) {
    __syncthreads();
    #pragma unroll
    for (int r = 0; r < 2; ++r) {
      const int flat = ((r << 8) + tid) << 3;       // 8 ushorts per rep
      const int rrow = flat >> 5, rcol = flat & 31;
      *(uint4*)(&As[0][0] + flat) =
          *(const uint4*)(A + (size_t)(row0 + rrow) * K + k0 + rcol);
      *(uint4*)(&Bs[0][0] + flat) =
          *(const uint4*)(WT + (size_t)(col0 + rrow) * K + k0 + rcol);
    }
    __syncthreads();
    bf16x8 af[4], bfr[4];
    #pragma unroll
    for (int m = 0; m < 4; ++m) af[m] = *(const bf16x8*)&As[wm + (m << 4) + lr][lk];
    #pragma unroll
    for (int n = 0; n < 4; ++n) bfr[n] = *(const bf16x8*)&Bs[wn + (n << 4) + lr][lk];
    #pragma unroll
    for (int m = 0; m < 4; ++m)
      #pragma unroll
      for (int n = 0; n < 4; ++n)
        acc[m][n] = __builtin_amdgcn_mfma_f32_16x16x32_bf16(af[m], bfr[n], acc[m][n], 0, 0, 0);
  }
  float* Cf = (float*)Cout;
  unsigned short* Cb = (unsigned short*)Cout;
  #pragma unroll
  for (int m = 0; m < 4; ++m) {
    #pragma unroll
    for (int n = 0; n < 4; ++n) {
      const int col = col0 + wn + (n << 4) + lr;
      const float bv = BIAS ? bias[col] : 0.0f;
      #pragma unroll
      for (int r = 0; r < 4; ++r) {
        const int row = row0 + wm + (m << 4) + ((lane >> 4) << 2) + r;
        float val = acc[m][n][r] + bv;
        if (RELU) val = fmaxf(val, 0.0f);
        if (RES)  val += res[(size_t)row * ldc + col];
        if (OBF16) Cb[(size_t)row * ldc + col] = f2bf(val);
        else       Cf[(size_t)row * ldc + col] = val;
      }
    }
  }
}

// ---------------- causal attention, one block per (b,h,t) -----------------
// qkv packed [2048][3072] f32 (q|k|v); out ob bf16 [2048][1024]
__global__ __launch_bounds__(256) void attn_k(const float* __restrict__ qkv,
                                              unsigned short* __restrict__ ob) {
  const int t = blockIdx.x, h = blockIdx.y, b = blockIdx.z;
  const int tid = threadIdx.x;
  __shared__ float qsh[64];
  __shared__ float sc[1024];
  __shared__ float red[256];
  const size_t rowbase = ((size_t)b * T_SEQ) * 3072;
  if (tid < 64) qsh[tid] = qkv[rowbase + (size_t)t * 3072 + h * 64 + tid];
  __syncthreads();
  float lmax = -3.4e38f;
  for (int s = tid; s <= t; s += 256) {
    const float* kr = qkv + rowbase + (size_t)s * 3072 + 1024 + h * 64;
    float a = 0.f;
    #pragma unroll
    for (int d = 0; d < 64; d += 4) {
      const float4 k4 = *(const float4*)(kr + d);
      a += qsh[d] * k4.x + qsh[d + 1] * k4.y + qsh[d + 2] * k4.z + qsh[d + 3] * k4.w;
    }
    a *= 0.125f;                       // 1/sqrt(64)
    sc[s] = a;
    lmax = fmaxf(lmax, a);
  }
  red[tid] = lmax;
  __syncthreads();
  #pragma unroll
  for (int off = 128; off; off >>= 1) {
    if (tid < off) red[tid] = fmaxf(red[tid], red[tid + off]);
    __syncthreads();
  }
  const float mx = red[0];
  __syncthreads();
  float lsum = 0.f;
  for (int s = tid; s <= t; s += 256) {
    const float p = __expf(sc[s] - mx);
    sc[s] = p;
    lsum += p;
  }
  red[tid] = lsum;
  __syncthreads();
  #pragma unroll
  for (int off = 128; off; off >>= 1) {
    if (tid < off) red[tid] += red[tid + off];
    __syncthreads();
  }
  const float inv = 1.0f / red[0];
  __syncthreads();
  const int d = tid & 63, g = tid >> 6;
  float a = 0.f;
  for (int s = g; s <= t; s += 4)
    a += sc[s] * qkv[rowbase + (size_t)s * 3072 + 2048 + h * 64 + d];
  red[(g << 6) + d] = a;
  __syncthreads();
  if (g == 0) {
    const float r = (red[d] + red[64 + d] + red[128 + d] + red[192 + d]) * inv;
    ob[((size_t)b * T_SEQ + t) * E_DIM + h * 64 + d] = f2bf(r);
  }
}

extern "C" void kernel_launch(void* const* d_in, const int* in_sizes, int n_in,
                              void* d_out, int out_size, void* d_ws, size_t ws_size,
                              hipStream_t stream) {
  (void)in_sizes; (void)n_in; (void)out_size; (void)ws_size;
  const int*   idx    = (const int*)d_in[0];
  const float* tok_w  = (const float*)d_in[1];
  const float* pos    = (const float*)d_in[2];
  const float* ln1_s  = (const float*)d_in[3];
  const float* ln1_b  = (const float*)d_in[4];
  const float* wq     = (const float*)d_in[5];
  const float* wk     = (const float*)d_in[6];
  const float* wv     = (const float*)d_in[7];
  const float* wo     = (const float*)d_in[8];
  const float* bo     = (const float*)d_in[9];
  const float* ln2_s  = (const float*)d_in[10];
  const float* ln2_b  = (const float*)d_in[11];
  const float* w1     = (const float*)d_in[12];
  const float* b1     = (const float*)d_in[13];
  const float* w2     = (const float*)d_in[14];
  const float* b2     = (const float*)d_in[15];
  const float* lnf_s  = (const float*)d_in[16];
  const float* lnf_b  = (const float*)d_in[17];
  const float* head_w = (const float*)d_in[18];
  const float* head_b = (const float*)d_in[19];
  float* out = (float*)d_out;

  char* p = (char*)d_ws;
  float* x            = (float*)p;          p += (size_t)M_ROWS * E_DIM * 4;   // 8 MB
  float* qkvb         = (float*)p;          p += (size_t)M_ROWS * 3072 * 4;    // 25 MB
  unsigned short* h   = (unsigned short*)p; p += (size_t)M_ROWS * E_DIM * 2;   // 4 MB
  unsigned short* obuf= (unsigned short*)p; p += (size_t)M_ROWS * E_DIM * 2;   // 4 MB
  unsigned short* ff  = (unsigned short*)p; p += (size_t)M_ROWS * FF_DIM * 2;  // 16 MB
  unsigned short* wt  = (unsigned short*)p; p += (size_t)16000 * E_DIM * 2;    // 32.8 MB

  embed_k<<<M_ROWS, 256, 0, stream>>>(idx, tok_w, pos, x);

  for (int l = 0; l < L_NUM; ++l) {
    const size_t lEE = (size_t)l * E_DIM * E_DIM;
    const size_t lEF = (size_t)l * E_DIM * FF_DIM;
    // ---- LN1 ----
    ln_k<<<M_ROWS, 256, 0, stream>>>(x, ln1_s + l * E_DIM, ln1_b + l * E_DIM, h);
    // ---- QKV (fused, N = 3072) ----
    transpose_k<<<dim3(32, 32), 256, 0, stream>>>(wq + lEE, wt,               E_DIM, E_DIM);
    transpose_k<<<dim3(32, 32), 256, 0, stream>>>(wk + lEE, wt + 1048576,     E_DIM, E_DIM);
    transpose_k<<<dim3(32, 32), 256, 0, stream>>>(wv + lEE, wt + 2097152,     E_DIM, E_DIM);
    gemm_k<false,false,false,false><<<dim3(24, 16), 256, 0, stream>>>(
        h, wt, nullptr, nullptr, qkvb, 3072, E_DIM);
    // ---- attention ----
    attn_k<<<dim3(T_SEQ, H_NUM, B_NUM), 256, 0, stream>>>(qkvb, obuf);
    // ---- out-proj + bias + residual into x ----
    transpose_k<<<dim3(32, 32), 256, 0, stream>>>(wo + lEE, wt, E_DIM, E_DIM);
    gemm_k<false,true,true,false><<<dim3(8, 16), 256, 0, stream>>>(
        obuf, wt, bo + l * E_DIM, x, x, E_DIM, E_DIM);
    // ---- LN2 ----
    ln_k<<<M_ROWS, 256, 0, stream>>>(x, ln2_s + l * E_DIM, ln2_b + l * E_DIM, h);
    // ---- MLP up + ReLU (bf16 out) ----
    transpose_k<<<dim3(128, 32), 256, 0, stream>>>(w1 + lEF, wt, E_DIM, FF_DIM);
    gemm_k<true,true,false,true><<<dim3(32, 16), 256, 0, stream>>>(
        h, wt, b1 + l * FF_DIM, nullptr, ff, FF_DIM, E_DIM);
    // ---- MLP down + bias + residual into x ----
    transpose_k<<<dim3(32, 128), 256, 0, stream>>>(w2 + lEF, wt, FF_DIM, E_DIM);
    gemm_k<false,true,true,false><<<dim3(8, 16), 256, 0, stream>>>(
        ff, wt, b2 + l * E_DIM, x, x, E_DIM, FF_DIM);
  }

  // ---- final LN + head (2 column chunks of 16000 to bound ws use) ----
  ln_k<<<M_ROWS, 256, 0, stream>>>(x, lnf_s, lnf_b, h);
  for (int c = 0; c < 2; ++c) {
    const int off = c * 16000;
    transpose_k<<<dim3(500, 32), 256, 0, stream>>>(head_w + off, wt, E_DIM, 32000);
    gemm_k<false,true,false,false><<<dim3(125, 16), 256, 0, stream>>>(
        h, wt, head_b + off, nullptr, out + off, 32000, E_DIM);
  }
}

// Round 2
// 1940.326 us; speedup vs baseline: 3.6552x; 3.6552x over previous
//
#include <hip/hip_runtime.h>

// GPT forward, MI355X. f32 inputs; bf16 MFMA GEMMs with f32 accum;
// LN/softmax/residual kept in f32. MFMA flash attention.

#define T_SEQ 1024
#define E_DIM 1024
#define H_NUM 16
#define D_HEAD 64
#define L_NUM 6
#define FF_DIM 4096
#define B_NUM 2
#define M_ROWS 2048   // B*T

using bf16x8 = __attribute__((ext_vector_type(8))) __bf16;
using f32x4  = __attribute__((ext_vector_type(4))) float;

__device__ __forceinline__ unsigned short f2bf(float f) {
  unsigned int u = __float_as_uint(f);
  u += 0x7fffu + ((u >> 16) & 1u);   // RNE
  return (unsigned short)(u >> 16);
}

// ---------------- embed: x[b*T+t][e] = tok_w[idx][e] + pos[t][e] ----------
__global__ __launch_bounds__(256) void embed_k(const int* __restrict__ idx,
                                               const float* __restrict__ tok_w,
                                               const float* __restrict__ pos,
                                               float* __restrict__ x) {
  const int i = blockIdx.x;            // 0..2047
  const int t = i & (T_SEQ - 1);
  const int tok = idx[i];
  const float4 a = ((const float4*)(tok_w + (size_t)tok * E_DIM))[threadIdx.x];
  const float4 p = ((const float4*)(pos + (size_t)t * E_DIM))[threadIdx.x];
  float4 o;
  o.x = a.x + p.x; o.y = a.y + p.y; o.z = a.z + p.z; o.w = a.w + p.w;
  ((float4*)(x + (size_t)i * E_DIM))[threadIdx.x] = o;
}

// ---------------- layernorm: f32 in -> bf16 out ---------------------------
__global__ __launch_bounds__(256) void ln_k(const float* __restrict__ x,
                                            const float* __restrict__ s,
                                            const float* __restrict__ b,
                                            unsigned short* __restrict__ out) {
  const int row = blockIdx.x, tid = threadIdx.x;
  const float4 v = ((const float4*)(x + (size_t)row * E_DIM))[tid];
  float sum = v.x + v.y + v.z + v.w;
  float sq  = v.x * v.x + v.y * v.y + v.z * v.z + v.w * v.w;
  #pragma unroll
  for (int off = 32; off; off >>= 1) {
    sum += __shfl_down(sum, off);
    sq  += __shfl_down(sq, off);
  }
  __shared__ float sm[10];
  const int wave = tid >> 6, lane = tid & 63;
  if (lane == 0) { sm[wave] = sum; sm[4 + wave] = sq; }
  __syncthreads();
  if (tid == 0) {
    const float ts = sm[0] + sm[1] + sm[2] + sm[3];
    const float tq = sm[4] + sm[5] + sm[6] + sm[7];
    const float mean = ts * (1.0f / E_DIM);
    const float var = tq * (1.0f / E_DIM) - mean * mean;
    sm[8] = mean;
    sm[9] = 1.0f / sqrtf(var + 1e-5f);
  }
  __syncthreads();
  const float mean = sm[8], inv = sm[9];
  const float4 sv = ((const float4*)s)[tid];
  const float4 bv = ((const float4*)b)[tid];
  ushort4 o;
  o.x = f2bf((v.x - mean) * inv * sv.x + bv.x);
  o.y = f2bf((v.y - mean) * inv * sv.y + bv.y);
  o.z = f2bf((v.z - mean) * inv * sv.z + bv.z);
  o.w = f2bf((v.w - mean) * inv * sv.w + bv.w);
  *(ushort4*)(out + (size_t)row * E_DIM + (tid << 2)) = o;
}

// ---------------- transpose + f32->bf16: WT[n][k] = W[k][n] ---------------
__global__ __launch_bounds__(256) void transpose_k(const float* __restrict__ W,
                                                   unsigned short* __restrict__ WT,
                                                   int K, int ldw) {
  __shared__ float tile[32][33];
  const int n0 = blockIdx.x << 5, k0 = blockIdx.y << 5;
  const int tx = threadIdx.x & 31, ty = threadIdx.x >> 5;
  #pragma unroll
  for (int i = ty; i < 32; i += 8)
    tile[i][tx] = W[(size_t)(k0 + i) * ldw + n0 + tx];
  __syncthreads();
  #pragma unroll
  for (int i = ty; i < 32; i += 8)
    WT[(size_t)(n0 + i) * K + k0 + tx] = f2bf(tile[tx][i]);
}

// ---------------- bf16 MFMA GEMM: C[M,N] = A[M,K] @ WT[N,K]^T -------------
// 128x128 tile, BK=32, 4 waves, 16x16x32_bf16, 4x4 frags per wave.
// LDS rows padded to 40 elems (80 B) -> 2-way bank aliasing on frag reads.
template<bool RELU, bool BIAS, bool RES, bool OBF16>
__global__ __launch_bounds__(256) void gemm_k(const unsigned short* __restrict__ A,
                                              const unsigned short* __restrict__ WT,
                                              const float* __restrict__ bias,
                                              const float* __restrict__ res,
                                              void* __restrict__ Cout,
                                              int ldc, int K) {
  __shared__ __align__(16) unsigned short As[128][40];
  __shared__ __align__(16) unsigned short Bs[128][40];
  const int tid = threadIdx.x;
  const int row0 = blockIdx.y << 7, col0 = blockIdx.x << 7;
  const int wave = tid >> 6, lane = tid & 63;
  const int wm = (wave >> 1) << 6, wn = (wave & 1) << 6;
  const int lr = lane & 15, lk = (lane >> 4) << 3;
  f32x4 acc[4][4] = {};
  for (int k0 = 0; k0 < K; k0 += 32) {
    __syncthreads();
    #pragma unroll
    for (int r = 0; r < 2; ++r) {
      const int flat = ((r << 8) + tid) << 3;       // 8 ushorts per rep
      const int rrow = flat >> 5, rcol = flat & 31;
      *(uint4*)&As[rrow][rcol] =
          *(const uint4*)(A + (size_t)(row0 + rrow) * K + k0 + rcol);
      *(uint4*)&Bs[rrow][rcol] =
          *(const uint4*)(WT + (size_t)(col0 + rrow) * K + k0 + rcol);
    }
    __syncthreads();
    bf16x8 af[4], bfr[4];
    #pragma unroll
    for (int m = 0; m < 4; ++m) af[m] = *(const bf16x8*)&As[wm + (m << 4) + lr][lk];
    #pragma unroll
    for (int n = 0; n < 4; ++n) bfr[n] = *(const bf16x8*)&Bs[wn + (n << 4) + lr][lk];
    #pragma unroll
    for (int m = 0; m < 4; ++m)
      #pragma unroll
      for (int n = 0; n < 4; ++n)
        acc[m][n] = __builtin_amdgcn_mfma_f32_16x16x32_bf16(af[m], bfr[n], acc[m][n], 0, 0, 0);
  }
  float* Cf = (float*)Cout;
  unsigned short* Cb = (unsigned short*)Cout;
  #pragma unroll
  for (int m = 0; m < 4; ++m) {
    #pragma unroll
    for (int n = 0; n < 4; ++n) {
      const int col = col0 + wn + (n << 4) + lr;
      const float bv = BIAS ? bias[col] : 0.0f;
      #pragma unroll
      for (int r = 0; r < 4; ++r) {
        const int row = row0 + wm + (m << 4) + ((lane >> 4) << 2) + r;
        float val = acc[m][n][r] + bv;
        if (RELU) val = fmaxf(val, 0.0f);
        if (RES)  val += res[(size_t)row * ldc + col];
        if (OBF16) Cb[(size_t)row * ldc + col] = f2bf(val);
        else       Cf[(size_t)row * ldc + col] = val;
      }
    }
  }
}

// ---------------- MFMA flash attention ------------------------------------
// qkv bf16 [2048][3072] (q|k|v), ob bf16 [2048][1024].
// Block = (q-tile 64 rows, head, batch); 4 waves, wave owns 16 q rows.
#define QBLK 64
#define KBLK 64
__global__ __launch_bounds__(256) void fattn_k(const unsigned short* __restrict__ qkv,
                                               unsigned short* __restrict__ ob) {
  const int qt = blockIdx.x, h = blockIdx.y, b = blockIdx.z;
  const int tid = threadIdx.x;
  const int wave = tid >> 6, lane = tid & 63;
  const int lr = lane & 15, lg = lane >> 4;      // lg = 0..3
  const int q0 = qt * QBLK;

  __shared__ __align__(16) unsigned short Qs[QBLK][72];
  __shared__ __align__(16) unsigned short Ks[KBLK][72];
  __shared__ __align__(16) unsigned short Vt[D_HEAD][72];   // transposed V
  __shared__ __align__(16) unsigned short Ps[QBLK][72];

  const size_t base = (size_t)b * T_SEQ * 3072 + (size_t)h * 64;
  const int srow = tid >> 3, scol = (tid & 7) << 3;

  // stage Q tile
  #pragma unroll
  for (int it = 0; it < 2; ++it) {
    const int row = srow + it * 32;
    *(uint4*)&Qs[row][scol] =
        *(const uint4*)(qkv + base + (size_t)(q0 + row) * 3072 + scol);
  }
  __syncthreads();
  bf16x8 qf[2];
  #pragma unroll
  for (int ks = 0; ks < 2; ++ks)
    qf[ks] = *(const bf16x8*)&Qs[wave * 16 + lr][ks * 32 + lg * 8];

  f32x4 acc_o[4] = {};
  float mrow[4], lrow[4];
  #pragma unroll
  for (int r = 0; r < 4; ++r) { mrow[r] = -3.0e38f; lrow[r] = 0.f; }

  const int ntile = qt + 1;
  for (int kt = 0; kt < ntile; ++kt) {
    const int s0 = kt * KBLK;
    __syncthreads();   // previous iteration done with Ks/Vt/Ps
    #pragma unroll
    for (int it = 0; it < 2; ++it) {
      const int row = srow + it * 32;
      *(uint4*)&Ks[row][scol] =
          *(const uint4*)(qkv + base + 1024 + (size_t)(s0 + row) * 3072 + scol);
      uint4 v4 = *(const uint4*)(qkv + base + 2048 + (size_t)(s0 + row) * 3072 + scol);
      const unsigned short* vs = (const unsigned short*)&v4;
      #pragma unroll
      for (int j = 0; j < 8; ++j) Vt[scol + j][row] = vs[j];
    }
    __syncthreads();

    // S = Q K^T (per wave: 16 q rows x 64 s cols)
    f32x4 sacc[4] = {};
    #pragma unroll
    for (int ks = 0; ks < 2; ++ks) {
      #pragma unroll
      for (int nf = 0; nf < 4; ++nf) {
        bf16x8 kf = *(const bf16x8*)&Ks[nf * 16 + lr][ks * 32 + lg * 8];
        sacc[nf] = __builtin_amdgcn_mfma_f32_16x16x32_bf16(qf[ks], kf, sacc[nf], 0, 0, 0);
      }
    }
    float sv[4][4];
    #pragma unroll
    for (int nf = 0; nf < 4; ++nf)
      #pragma unroll
      for (int r = 0; r < 4; ++r) sv[nf][r] = sacc[nf][r] * 0.125f;
    if (kt == ntile - 1) {         // diagonal tile: causal mask
      #pragma unroll
      for (int nf = 0; nf < 4; ++nf) {
        const int s = s0 + nf * 16 + lr;
        #pragma unroll
        for (int r = 0; r < 4; ++r) {
          const int q = q0 + wave * 16 + lg * 4 + r;
          if (s > q) sv[nf][r] = -3.0e38f;
        }
      }
    }
    // online softmax per q-row (rows live in 16-lane groups)
    float p[4][4];
    #pragma unroll
    for (int r = 0; r < 4; ++r) {
      float mx = fmaxf(fmaxf(sv[0][r], sv[1][r]), fmaxf(sv[2][r], sv[3][r]));
      #pragma unroll
      for (int off = 1; off < 16; off <<= 1) mx = fmaxf(mx, __shfl_xor(mx, off));
      const float mnew = fmaxf(mrow[r], mx);
      const float alpha = __expf(mrow[r] - mnew);
      mrow[r] = mnew;
      float sum = 0.f;
      #pragma unroll
      for (int nf = 0; nf < 4; ++nf) {
        p[nf][r] = __expf(sv[nf][r] - mnew);
        sum += p[nf][r];
      }
      #pragma unroll
      for (int off = 1; off < 16; off <<= 1) sum += __shfl_xor(sum, off);
      lrow[r] = lrow[r] * alpha + sum;
      #pragma unroll
      for (int df = 0; df < 4; ++df) acc_o[df][r] *= alpha;
    }
    // stage P (bf16) for the PV MFMA
    #pragma unroll
    for (int nf = 0; nf < 4; ++nf)
      #pragma unroll
      for (int r = 0; r < 4; ++r)
        Ps[wave * 16 + lg * 4 + r][nf * 16 + lr] = f2bf(p[nf][r]);
    __syncthreads();
    // O += P V
    #pragma unroll
    for (int ks = 0; ks < 2; ++ks) {
      bf16x8 pa = *(const bf16x8*)&Ps[wave * 16 + lr][ks * 32 + lg * 8];
      #pragma unroll
      for (int df = 0; df < 4; ++df) {
        bf16x8 vf = *(const bf16x8*)&Vt[df * 16 + lr][ks * 32 + lg * 8];
        acc_o[df] = __builtin_amdgcn_mfma_f32_16x16x32_bf16(pa, vf, acc_o[df], 0, 0, 0);
      }
    }
  }
  // epilogue: O / l -> ob
  #pragma unroll
  for (int r = 0; r < 4; ++r) {
    const float inv = 1.0f / lrow[r];
    const int row = q0 + wave * 16 + lg * 4 + r;
    #pragma unroll
    for (int df = 0; df < 4; ++df)
      ob[((size_t)b * T_SEQ + row) * E_DIM + h * 64 + df * 16 + lr] =
          f2bf(acc_o[df][r] * inv);
  }
}

extern "C" void kernel_launch(void* const* d_in, const int* in_sizes, int n_in,
                              void* d_out, int out_size, void* d_ws, size_t ws_size,
                              hipStream_t stream) {
  (void)in_sizes; (void)n_in; (void)out_size; (void)ws_size;
  const int*   idx    = (const int*)d_in[0];
  const float* tok_w  = (const float*)d_in[1];
  const float* pos    = (const float*)d_in[2];
  const float* ln1_s  = (const float*)d_in[3];
  const float* ln1_b  = (const float*)d_in[4];
  const float* wq     = (const float*)d_in[5];
  const float* wk     = (const float*)d_in[6];
  const float* wv     = (const float*)d_in[7];
  const float* wo     = (const float*)d_in[8];
  const float* bo     = (const float*)d_in[9];
  const float* ln2_s  = (const float*)d_in[10];
  const float* ln2_b  = (const float*)d_in[11];
  const float* w1     = (const float*)d_in[12];
  const float* b1     = (const float*)d_in[13];
  const float* w2     = (const float*)d_in[14];
  const float* b2     = (const float*)d_in[15];
  const float* lnf_s  = (const float*)d_in[16];
  const float* lnf_b  = (const float*)d_in[17];
  const float* head_w = (const float*)d_in[18];
  const float* head_b = (const float*)d_in[19];
  float* out = (float*)d_out;

  char* p = (char*)d_ws;
  float* x            = (float*)p;          p += (size_t)M_ROWS * E_DIM * 4;   // 8 MB
  unsigned short* qkvb= (unsigned short*)p; p += (size_t)M_ROWS * 3072 * 4;    // bf16, slot kept 25 MB
  unsigned short* h   = (unsigned short*)p; p += (size_t)M_ROWS * E_DIM * 2;   // 4 MB
  unsigned short* obuf= (unsigned short*)p; p += (size_t)M_ROWS * E_DIM * 2;   // 4 MB
  unsigned short* ff  = (unsigned short*)p; p += (size_t)M_ROWS * FF_DIM * 2;  // 16 MB
  unsigned short* wt  = (unsigned short*)p; p += (size_t)16000 * E_DIM * 2;    // 32.8 MB

  embed_k<<<M_ROWS, 256, 0, stream>>>(idx, tok_w, pos, x);

  for (int l = 0; l < L_NUM; ++l) {
    const size_t lEE = (size_t)l * E_DIM * E_DIM;
    const size_t lEF = (size_t)l * E_DIM * FF_DIM;
    // ---- LN1 ----
    ln_k<<<M_ROWS, 256, 0, stream>>>(x, ln1_s + l * E_DIM, ln1_b + l * E_DIM, h);
    // ---- QKV (fused, N = 3072, bf16 out) ----
    transpose_k<<<dim3(32, 32), 256, 0, stream>>>(wq + lEE, wt,               E_DIM, E_DIM);
    transpose_k<<<dim3(32, 32), 256, 0, stream>>>(wk + lEE, wt + 1048576,     E_DIM, E_DIM);
    transpose_k<<<dim3(32, 32), 256, 0, stream>>>(wv + lEE, wt + 2097152,     E_DIM, E_DIM);
    gemm_k<false,false,false,true><<<dim3(24, 16), 256, 0, stream>>>(
        h, wt, nullptr, nullptr, qkvb, 3072, E_DIM);
    // ---- flash attention ----
    fattn_k<<<dim3(T_SEQ / QBLK, H_NUM, B_NUM), 256, 0, stream>>>(qkvb, obuf);
    // ---- out-proj + bias + residual into x ----
    transpose_k<<<dim3(32, 32), 256, 0, stream>>>(wo + lEE, wt, E_DIM, E_DIM);
    gemm_k<false,true,true,false><<<dim3(8, 16), 256, 0, stream>>>(
        obuf, wt, bo + l * E_DIM, x, x, E_DIM, E_DIM);
    // ---- LN2 ----
    ln_k<<<M_ROWS, 256, 0, stream>>>(x, ln2_s + l * E_DIM, ln2_b + l * E_DIM, h);
    // ---- MLP up + ReLU (bf16 out) ----
    transpose_k<<<dim3(128, 32), 256, 0, stream>>>(w1 + lEF, wt, E_DIM, FF_DIM);
    gemm_k<true,true,false,true><<<dim3(32, 16), 256, 0, stream>>>(
        h, wt, b1 + l * FF_DIM, nullptr, ff, FF_DIM, E_DIM);
    // ---- MLP down + bias + residual into x ----
    transpose_k<<<dim3(32, 128), 256, 0, stream>>>(w2 + lEF, wt, FF_DIM, E_DIM);
    gemm_k<false,true,true,false><<<dim3(8, 16), 256, 0, stream>>>(
        ff, wt, b2 + l * E_DIM, x, x, E_DIM, FF_DIM);
  }

  // ---- final LN + head (2 column chunks of 16000 to bound ws use) ----
  ln_k<<<M_ROWS, 256, 0, stream>>>(x, lnf_s, lnf_b, h);
  for (int c = 0; c < 2; ++c) {
    const int off = c * 16000;
    transpose_k<<<dim3(500, 32), 256, 0, stream>>>(head_w + off, wt, E_DIM, 32000);
    gemm_k<false,true,false,false><<<dim3(125, 16), 256, 0, stream>>>(
        h, wt, head_b + off, nullptr, out + off, 32000, E_DIM);
  }
}

// Round 3
// 1588.174 us; speedup vs baseline: 4.4657x; 1.2217x over previous
//
#include <hip/hip_runtime.h>

// GPT forward, MI355X. f32 inputs; bf16 MFMA GEMMs with f32 accum;
// LN/softmax/residual kept in f32. MFMA flash attention.
// GEMM: 128xN tile, BK=64, global_load_lds staging, XOR-swizzled LDS.

#define T_SEQ 1024
#define E_DIM 1024
#define H_NUM 16
#define D_HEAD 64
#define L_NUM 6
#define FF_DIM 4096
#define B_NUM 2
#define M_ROWS 2048   // B*T

using bf16x8 = __attribute__((ext_vector_type(8))) __bf16;
using f32x4  = __attribute__((ext_vector_type(4))) float;

__device__ __forceinline__ unsigned short f2bf(float f) {
  unsigned int u = __float_as_uint(f);
  u += 0x7fffu + ((u >> 16) & 1u);   // RNE
  return (unsigned short)(u >> 16);
}

// async global->LDS, 16B per lane. lptr must be wave-uniform (HW adds lane*16).
__device__ __forceinline__ void gload_lds16(const void* g, void* l) {
  __builtin_amdgcn_global_load_lds(
      (const __attribute__((address_space(1))) unsigned int*)g,
      (__attribute__((address_space(3))) unsigned int*)l, 16, 0, 0);
}

// ---------------- embed: x[b*T+t][e] = tok_w[idx][e] + pos[t][e] ----------
__global__ __launch_bounds__(256) void embed_k(const int* __restrict__ idx,
                                               const float* __restrict__ tok_w,
                                               const float* __restrict__ pos,
                                               float* __restrict__ x) {
  const int i = blockIdx.x;            // 0..2047
  const int t = i & (T_SEQ - 1);
  const int tok = idx[i];
  const float4 a = ((const float4*)(tok_w + (size_t)tok * E_DIM))[threadIdx.x];
  const float4 p = ((const float4*)(pos + (size_t)t * E_DIM))[threadIdx.x];
  float4 o;
  o.x = a.x + p.x; o.y = a.y + p.y; o.z = a.z + p.z; o.w = a.w + p.w;
  ((float4*)(x + (size_t)i * E_DIM))[threadIdx.x] = o;
}

// ---------------- layernorm: f32 in -> bf16 out ---------------------------
__global__ __launch_bounds__(256) void ln_k(const float* __restrict__ x,
                                            const float* __restrict__ s,
                                            const float* __restrict__ b,
                                            unsigned short* __restrict__ out) {
  const int row = blockIdx.x, tid = threadIdx.x;
  const float4 v = ((const float4*)(x + (size_t)row * E_DIM))[tid];
  float sum = v.x + v.y + v.z + v.w;
  float sq  = v.x * v.x + v.y * v.y + v.z * v.z + v.w * v.w;
  #pragma unroll
  for (int off = 32; off; off >>= 1) {
    sum += __shfl_down(sum, off);
    sq  += __shfl_down(sq, off);
  }
  __shared__ float sm[10];
  const int wave = tid >> 6, lane = tid & 63;
  if (lane == 0) { sm[wave] = sum; sm[4 + wave] = sq; }
  __syncthreads();
  if (tid == 0) {
    const float ts = sm[0] + sm[1] + sm[2] + sm[3];
    const float tq = sm[4] + sm[5] + sm[6] + sm[7];
    const float mean = ts * (1.0f / E_DIM);
    const float var = tq * (1.0f / E_DIM) - mean * mean;
    sm[8] = mean;
    sm[9] = 1.0f / sqrtf(var + 1e-5f);
  }
  __syncthreads();
  const float mean = sm[8], inv = sm[9];
  const float4 sv = ((const float4*)s)[tid];
  const float4 bv = ((const float4*)b)[tid];
  ushort4 o;
  o.x = f2bf((v.x - mean) * inv * sv.x + bv.x);
  o.y = f2bf((v.y - mean) * inv * sv.y + bv.y);
  o.z = f2bf((v.z - mean) * inv * sv.z + bv.z);
  o.w = f2bf((v.w - mean) * inv * sv.w + bv.w);
  *(ushort4*)(out + (size_t)row * E_DIM + (tid << 2)) = o;
}

// ---------------- transpose + f32->bf16: WT[n][k] = W[k][n] ---------------
__global__ __launch_bounds__(256) void transpose_k(const float* __restrict__ W,
                                                   unsigned short* __restrict__ WT,
                                                   int K, int ldw) {
  __shared__ float tile[32][33];
  const int n0 = blockIdx.x << 5, k0 = blockIdx.y << 5;
  const int tx = threadIdx.x & 31, ty = threadIdx.x >> 5;
  #pragma unroll
  for (int i = ty; i < 32; i += 8)
    tile[i][tx] = W[(size_t)(k0 + i) * ldw + n0 + tx];
  __syncthreads();
  #pragma unroll
  for (int i = ty; i < 32; i += 8)
    WT[(size_t)(n0 + i) * K + k0 + tx] = f2bf(tile[tx][i]);
}

// ---------------- bf16 MFMA GEMM: C[M,N] = A[M,K] @ WT[N,K]^T -------------
// BM x 128 tile, BK=64, 4 waves. global_load_lds staging into linear LDS with
// inverse-swizzled global source; reads apply slot ^= row&7 (conflict-free).
template<int BM, bool RELU, bool BIAS, bool RES, bool OBF16>
__global__ __launch_bounds__(256) void gemm_k(const unsigned short* __restrict__ A,
                                              const unsigned short* __restrict__ WT,
                                              const float* __restrict__ bias,
                                              const float* __restrict__ res,
                                              void* __restrict__ Cout,
                                              int ldc, int K) {
  constexpr int BN = 128;
  constexpr int BK = 64;                    // 128 B rows = 8 slots of 16 B
  constexpr int MF = BM / 32;               // per-wave m frags (4 or 2)
  constexpr int AJ = (BM * BK * 2 / 1024) / 4;  // A chunk-issues per thread
  constexpr int BJ = (BN * BK * 2 / 1024) / 4;  // B chunk-issues per thread
  __shared__ __align__(16) unsigned short As[BM][BK];
  __shared__ __align__(16) unsigned short Bs[BN][BK];
  const int tid = threadIdx.x;
  const int row0 = blockIdx.y * BM, col0 = blockIdx.x * BN;
  const int wave = tid >> 6, lane = tid & 63;
  const int wm = (wave >> 1) * (BM / 2), wn = (wave & 1) * 64;
  const int lr = lane & 15, lg = lane >> 4;
  // staging geometry: chunk = 1 KB = 8 rows; lane covers (row, slot)
  const int src_in_chunk = lane >> 3;       // 0..7 row within chunk
  const int sslot = lane & 7;               // 0..7 16B slot
  f32x4 acc[MF][4] = {};
  for (int k0 = 0; k0 < K; k0 += BK) {
    __syncthreads();
    #pragma unroll
    for (int j = 0; j < AJ; ++j) {
      const int c = wave + 4 * j;
      const int row = c * 8 + src_in_chunk;
      const int sp = sslot ^ (row & 7);     // inverse-swizzled source slot
      gload_lds16(A + (size_t)(row0 + row) * K + k0 + sp * 8,
                  (char*)As + c * 1024);
    }
    #pragma unroll
    for (int j = 0; j < BJ; ++j) {
      const int c = wave + 4 * j;
      const int row = c * 8 + src_in_chunk;
      const int sp = sslot ^ (row & 7);
      gload_lds16(WT + (size_t)(col0 + row) * K + k0 + sp * 8,
                  (char*)Bs + c * 1024);
    }
    __syncthreads();
    #pragma unroll
    for (int ks = 0; ks < 2; ++ks) {
      bf16x8 af[MF], bfr[4];
      #pragma unroll
      for (int m = 0; m < MF; ++m) {
        const int r = wm + m * 16 + lr;
        const int s = (ks * 4 + lg) ^ (r & 7);
        af[m] = *(const bf16x8*)((const char*)As + r * 128 + s * 16);
      }
      #pragma unroll
      for (int n = 0; n < 4; ++n) {
        const int r = wn + n * 16 + lr;
        const int s = (ks * 4 + lg) ^ (r & 7);
        bfr[n] = *(const bf16x8*)((const char*)Bs + r * 128 + s * 16);
      }
      #pragma unroll
      for (int m = 0; m < MF; ++m)
        #pragma unroll
        for (int n = 0; n < 4; ++n)
          acc[m][n] = __builtin_amdgcn_mfma_f32_16x16x32_bf16(af[m], bfr[n], acc[m][n], 0, 0, 0);
    }
  }
  float* Cf = (float*)Cout;
  unsigned short* Cb = (unsigned short*)Cout;
  #pragma unroll
  for (int m = 0; m < MF; ++m) {
    #pragma unroll
    for (int n = 0; n < 4; ++n) {
      const int col = col0 + wn + (n << 4) + lr;
      const float bv = BIAS ? bias[col] : 0.0f;
      #pragma unroll
      for (int r = 0; r < 4; ++r) {
        const int row = row0 + wm + (m << 4) + (lg << 2) + r;
        float val = acc[m][n][r] + bv;
        if (RELU) val = fmaxf(val, 0.0f);
        if (RES)  val += res[(size_t)row * ldc + col];
        if (OBF16) Cb[(size_t)row * ldc + col] = f2bf(val);
        else       Cf[(size_t)row * ldc + col] = val;
      }
    }
  }
}

// ---------------- MFMA flash attention ------------------------------------
// qkv bf16 [2048][3072] (q|k|v), ob bf16 [2048][1024].
// Block = (q-tile 64 rows, head, batch); 4 waves, wave owns 16 q rows.
#define QBLK 64
#define KBLK 64
__global__ __launch_bounds__(256) void fattn_k(const unsigned short* __restrict__ qkv,
                                               unsigned short* __restrict__ ob) {
  const int qt = blockIdx.x, h = blockIdx.y, b = blockIdx.z;
  const int tid = threadIdx.x;
  const int wave = tid >> 6, lane = tid & 63;
  const int lr = lane & 15, lg = lane >> 4;      // lg = 0..3
  const int q0 = qt * QBLK;

  __shared__ __align__(16) unsigned short Qs[QBLK][72];
  __shared__ __align__(16) unsigned short Ks[KBLK][72];
  __shared__ __align__(16) unsigned short Vt[D_HEAD][72];   // transposed V
  __shared__ __align__(16) unsigned short Ps[QBLK][72];

  const size_t base = (size_t)b * T_SEQ * 3072 + (size_t)h * 64;
  const int srow = tid >> 3, scol = (tid & 7) << 3;

  // stage Q tile
  #pragma unroll
  for (int it = 0; it < 2; ++it) {
    const int row = srow + it * 32;
    *(uint4*)&Qs[row][scol] =
        *(const uint4*)(qkv + base + (size_t)(q0 + row) * 3072 + scol);
  }
  __syncthreads();
  bf16x8 qf[2];
  #pragma unroll
  for (int ks = 0; ks < 2; ++ks)
    qf[ks] = *(const bf16x8*)&Qs[wave * 16 + lr][ks * 32 + lg * 8];

  f32x4 acc_o[4] = {};
  float mrow[4], lrow[4];
  #pragma unroll
  for (int r = 0; r < 4; ++r) { mrow[r] = -3.0e38f; lrow[r] = 0.f; }

  const int ntile = qt + 1;
  for (int kt = 0; kt < ntile; ++kt) {
    const int s0 = kt * KBLK;
    __syncthreads();   // previous iteration done with Ks/Vt/Ps
    #pragma unroll
    for (int it = 0; it < 2; ++it) {
      const int row = srow + it * 32;
      *(uint4*)&Ks[row][scol] =
          *(const uint4*)(qkv + base + 1024 + (size_t)(s0 + row) * 3072 + scol);
      uint4 v4 = *(const uint4*)(qkv + base + 2048 + (size_t)(s0 + row) * 3072 + scol);
      const unsigned short* vs = (const unsigned short*)&v4;
      #pragma unroll
      for (int j = 0; j < 8; ++j) Vt[scol + j][row] = vs[j];
    }
    __syncthreads();

    // S = Q K^T (per wave: 16 q rows x 64 s cols)
    f32x4 sacc[4] = {};
    #pragma unroll
    for (int ks = 0; ks < 2; ++ks) {
      #pragma unroll
      for (int nf = 0; nf < 4; ++nf) {
        bf16x8 kf = *(const bf16x8*)&Ks[nf * 16 + lr][ks * 32 + lg * 8];
        sacc[nf] = __builtin_amdgcn_mfma_f32_16x16x32_bf16(qf[ks], kf, sacc[nf], 0, 0, 0);
      }
    }
    float sv[4][4];
    #pragma unroll
    for (int nf = 0; nf < 4; ++nf)
      #pragma unroll
      for (int r = 0; r < 4; ++r) sv[nf][r] = sacc[nf][r] * 0.125f;
    if (kt == ntile - 1) {         // diagonal tile: causal mask
      #pragma unroll
      for (int nf = 0; nf < 4; ++nf) {
        const int s = s0 + nf * 16 + lr;
        #pragma unroll
        for (int r = 0; r < 4; ++r) {
          const int q = q0 + wave * 16 + lg * 4 + r;
          if (s > q) sv[nf][r] = -3.0e38f;
        }
      }
    }
    // online softmax per q-row (rows live in 16-lane groups)
    float p[4][4];
    #pragma unroll
    for (int r = 0; r < 4; ++r) {
      float mx = fmaxf(fmaxf(sv[0][r], sv[1][r]), fmaxf(sv[2][r], sv[3][r]));
      #pragma unroll
      for (int off = 1; off < 16; off <<= 1) mx = fmaxf(mx, __shfl_xor(mx, off));
      const float mnew = fmaxf(mrow[r], mx);
      const float alpha = __expf(mrow[r] - mnew);
      mrow[r] = mnew;
      float sum = 0.f;
      #pragma unroll
      for (int nf = 0; nf < 4; ++nf) {
        p[nf][r] = __expf(sv[nf][r] - mnew);
        sum += p[nf][r];
      }
      #pragma unroll
      for (int off = 1; off < 16; off <<= 1) sum += __shfl_xor(sum, off);
      lrow[r] = lrow[r] * alpha + sum;
      #pragma unroll
      for (int df = 0; df < 4; ++df) acc_o[df][r] *= alpha;
    }
    // stage P (bf16) for the PV MFMA
    #pragma unroll
    for (int nf = 0; nf < 4; ++nf)
      #pragma unroll
      for (int r = 0; r < 4; ++r)
        Ps[wave * 16 + lg * 4 + r][nf * 16 + lr] = f2bf(p[nf][r]);
    __syncthreads();
    // O += P V
    #pragma unroll
    for (int ks = 0; ks < 2; ++ks) {
      bf16x8 pa = *(const bf16x8*)&Ps[wave * 16 + lr][ks * 32 + lg * 8];
      #pragma unroll
      for (int df = 0; df < 4; ++df) {
        bf16x8 vf = *(const bf16x8*)&Vt[df * 16 + lr][ks * 32 + lg * 8];
        acc_o[df] = __builtin_amdgcn_mfma_f32_16x16x32_bf16(pa, vf, acc_o[df], 0, 0, 0);
      }
    }
  }
  // epilogue: O / l -> ob
  #pragma unroll
  for (int r = 0; r < 4; ++r) {
    const float inv = 1.0f / lrow[r];
    const int row = q0 + wave * 16 + lg * 4 + r;
    #pragma unroll
    for (int df = 0; df < 4; ++df)
      ob[((size_t)b * T_SEQ + row) * E_DIM + h * 64 + df * 16 + lr] =
          f2bf(acc_o[df][r] * inv);
  }
}

extern "C" void kernel_launch(void* const* d_in, const int* in_sizes, int n_in,
                              void* d_out, int out_size, void* d_ws, size_t ws_size,
                              hipStream_t stream) {
  (void)in_sizes; (void)n_in; (void)out_size; (void)ws_size;
  const int*   idx    = (const int*)d_in[0];
  const float* tok_w  = (const float*)d_in[1];
  const float* pos    = (const float*)d_in[2];
  const float* ln1_s  = (const float*)d_in[3];
  const float* ln1_b  = (const float*)d_in[4];
  const float* wq     = (const float*)d_in[5];
  const float* wk     = (const float*)d_in[6];
  const float* wv     = (const float*)d_in[7];
  const float* wo     = (const float*)d_in[8];
  const float* bo     = (const float*)d_in[9];
  const float* ln2_s  = (const float*)d_in[10];
  const float* ln2_b  = (const float*)d_in[11];
  const float* w1     = (const float*)d_in[12];
  const float* b1     = (const float*)d_in[13];
  const float* w2     = (const float*)d_in[14];
  const float* b2     = (const float*)d_in[15];
  const float* lnf_s  = (const float*)d_in[16];
  const float* lnf_b  = (const float*)d_in[17];
  const float* head_w = (const float*)d_in[18];
  const float* head_b = (const float*)d_in[19];
  float* out = (float*)d_out;

  char* p = (char*)d_ws;
  float* x            = (float*)p;          p += (size_t)M_ROWS * E_DIM * 4;   // 8 MB
  unsigned short* qkvb= (unsigned short*)p; p += (size_t)M_ROWS * 3072 * 4;    // bf16 (slot 25 MB)
  unsigned short* h   = (unsigned short*)p; p += (size_t)M_ROWS * E_DIM * 2;   // 4 MB
  unsigned short* obuf= (unsigned short*)p; p += (size_t)M_ROWS * E_DIM * 2;   // 4 MB
  unsigned short* ff  = (unsigned short*)p; p += (size_t)M_ROWS * FF_DIM * 2;  // 16 MB
  unsigned short* wt  = (unsigned short*)p; p += (size_t)32000 * E_DIM * 2;    // 65.5 MB

  embed_k<<<M_ROWS, 256, 0, stream>>>(idx, tok_w, pos, x);

  for (int l = 0; l < L_NUM; ++l) {
    const size_t lEE = (size_t)l * E_DIM * E_DIM;
    const size_t lEF = (size_t)l * E_DIM * FF_DIM;
    // ---- LN1 ----
    ln_k<<<M_ROWS, 256, 0, stream>>>(x, ln1_s + l * E_DIM, ln1_b + l * E_DIM, h);
    // ---- QKV (fused, N = 3072, bf16 out) ----
    transpose_k<<<dim3(32, 32), 256, 0, stream>>>(wq + lEE, wt,               E_DIM, E_DIM);
    transpose_k<<<dim3(32, 32), 256, 0, stream>>>(wk + lEE, wt + 1048576,     E_DIM, E_DIM);
    transpose_k<<<dim3(32, 32), 256, 0, stream>>>(wv + lEE, wt + 2097152,     E_DIM, E_DIM);
    gemm_k<128,false,false,false,true><<<dim3(24, 16), 256, 0, stream>>>(
        h, wt, nullptr, nullptr, qkvb, 3072, E_DIM);
    // ---- flash attention ----
    fattn_k<<<dim3(T_SEQ / QBLK, H_NUM, B_NUM), 256, 0, stream>>>(qkvb, obuf);
    // ---- out-proj + bias + residual into x (BM=64: 256 blocks) ----
    transpose_k<<<dim3(32, 32), 256, 0, stream>>>(wo + lEE, wt, E_DIM, E_DIM);
    gemm_k<64,false,true,true,false><<<dim3(8, 32), 256, 0, stream>>>(
        obuf, wt, bo + l * E_DIM, x, x, E_DIM, E_DIM);
    // ---- LN2 ----
    ln_k<<<M_ROWS, 256, 0, stream>>>(x, ln2_s + l * E_DIM, ln2_b + l * E_DIM, h);
    // ---- MLP up + ReLU (bf16 out) ----
    transpose_k<<<dim3(128, 32), 256, 0, stream>>>(w1 + lEF, wt, E_DIM, FF_DIM);
    gemm_k<128,true,true,false,true><<<dim3(32, 16), 256, 0, stream>>>(
        h, wt, b1 + l * FF_DIM, nullptr, ff, FF_DIM, E_DIM);
    // ---- MLP down + bias + residual into x (BM=64: 256 blocks) ----
    transpose_k<<<dim3(32, 128), 256, 0, stream>>>(w2 + lEF, wt, FF_DIM, E_DIM);
    gemm_k<64,false,true,true,false><<<dim3(8, 32), 256, 0, stream>>>(
        ff, wt, b2 + l * E_DIM, x, x, E_DIM, FF_DIM);
  }

  // ---- final LN + head (single pass, N = 32000) ----
  ln_k<<<M_ROWS, 256, 0, stream>>>(x, lnf_s, lnf_b, h);
  transpose_k<<<dim3(1000, 32), 256, 0, stream>>>(head_w, wt, E_DIM, 32000);
  gemm_k<128,false,true,false,false><<<dim3(250, 16), 256, 0, stream>>>(
      h, wt, head_b, nullptr, out, 32000, E_DIM);
}

// Round 4
// 1525.277 us; speedup vs baseline: 4.6498x; 1.0412x over previous
//
#include <hip/hip_runtime.h>

// GPT forward, MI355X. f32 inputs; bf16 MFMA GEMMs with f32 accum;
// LN/softmax/residual kept in f32. MFMA flash attention.
// GEMM: BMx128 tile, BK=64, 2-phase double-buffered global_load_lds staging,
// XOR-swizzled LDS, m-fastest grid order for B-panel L2 reuse.

#define T_SEQ 1024
#define E_DIM 1024
#define H_NUM 16
#define D_HEAD 64
#define L_NUM 6
#define FF_DIM 4096
#define B_NUM 2
#define M_ROWS 2048   // B*T

using bf16x8 = __attribute__((ext_vector_type(8))) __bf16;
using f32x4  = __attribute__((ext_vector_type(4))) float;

__device__ __forceinline__ unsigned short f2bf(float f) {
  unsigned int u = __float_as_uint(f);
  u += 0x7fffu + ((u >> 16) & 1u);   // RNE
  return (unsigned short)(u >> 16);
}

// async global->LDS, 16B per lane. LDS dest is wave-uniform (HW adds lane*16).
__device__ __forceinline__ void gload_lds16(const void* g, void* l) {
  __builtin_amdgcn_global_load_lds(
      (const __attribute__((address_space(1))) unsigned int*)g,
      (__attribute__((address_space(3))) unsigned int*)l, 16, 0, 0);
}

// ---------------- embed: x[b*T+t][e] = tok_w[idx][e] + pos[t][e] ----------
__global__ __launch_bounds__(256) void embed_k(const int* __restrict__ idx,
                                               const float* __restrict__ tok_w,
                                               const float* __restrict__ pos,
                                               float* __restrict__ x) {
  const int i = blockIdx.x;            // 0..2047
  const int t = i & (T_SEQ - 1);
  const int tok = idx[i];
  const float4 a = ((const float4*)(tok_w + (size_t)tok * E_DIM))[threadIdx.x];
  const float4 p = ((const float4*)(pos + (size_t)t * E_DIM))[threadIdx.x];
  float4 o;
  o.x = a.x + p.x; o.y = a.y + p.y; o.z = a.z + p.z; o.w = a.w + p.w;
  ((float4*)(x + (size_t)i * E_DIM))[threadIdx.x] = o;
}

// ---------------- layernorm: f32 in -> bf16 out ---------------------------
__global__ __launch_bounds__(256) void ln_k(const float* __restrict__ x,
                                            const float* __restrict__ s,
                                            const float* __restrict__ b,
                                            unsigned short* __restrict__ out) {
  const int row = blockIdx.x, tid = threadIdx.x;
  const float4 v = ((const float4*)(x + (size_t)row * E_DIM))[tid];
  float sum = v.x + v.y + v.z + v.w;
  float sq  = v.x * v.x + v.y * v.y + v.z * v.z + v.w * v.w;
  #pragma unroll
  for (int off = 32; off; off >>= 1) {
    sum += __shfl_down(sum, off);
    sq  += __shfl_down(sq, off);
  }
  __shared__ float sm[10];
  const int wave = tid >> 6, lane = tid & 63;
  if (lane == 0) { sm[wave] = sum; sm[4 + wave] = sq; }
  __syncthreads();
  if (tid == 0) {
    const float ts = sm[0] + sm[1] + sm[2] + sm[3];
    const float tq = sm[4] + sm[5] + sm[6] + sm[7];
    const float mean = ts * (1.0f / E_DIM);
    const float var = tq * (1.0f / E_DIM) - mean * mean;
    sm[8] = mean;
    sm[9] = 1.0f / sqrtf(var + 1e-5f);
  }
  __syncthreads();
  const float mean = sm[8], inv = sm[9];
  const float4 sv = ((const float4*)s)[tid];
  const float4 bv = ((const float4*)b)[tid];
  ushort4 o;
  o.x = f2bf((v.x - mean) * inv * sv.x + bv.x);
  o.y = f2bf((v.y - mean) * inv * sv.y + bv.y);
  o.z = f2bf((v.z - mean) * inv * sv.z + bv.z);
  o.w = f2bf((v.w - mean) * inv * sv.w + bv.w);
  *(ushort4*)(out + (size_t)row * E_DIM + (tid << 2)) = o;
}

// ---------------- transpose + f32->bf16: WT[n][k] = W[k][n] ---------------
__global__ __launch_bounds__(256) void transpose_k(const float* __restrict__ W,
                                                   unsigned short* __restrict__ WT,
                                                   int K, int ldw) {
  __shared__ float tile[32][33];
  const int n0 = blockIdx.x << 5, k0 = blockIdx.y << 5;
  const int tx = threadIdx.x & 31, ty = threadIdx.x >> 5;
  #pragma unroll
  for (int i = ty; i < 32; i += 8)
    tile[i][tx] = W[(size_t)(k0 + i) * ldw + n0 + tx];
  __syncthreads();
  #pragma unroll
  for (int i = ty; i < 32; i += 8)
    WT[(size_t)(n0 + i) * K + k0 + tx] = f2bf(tile[tx][i]);
}

// ---------------- bf16 MFMA GEMM: C[M,N] = A[M,K] @ WT[N,K]^T -------------
// BM x 128 tile, BK=64, 4 waves, double-buffered LDS, one barrier per K-step.
// Grid: blockIdx.x = m-block (fastest) so resident blocks share B panels.
template<int BM, bool RELU, bool BIAS, bool RES, bool OBF16>
__global__ __launch_bounds__(256) void gemm_k(const unsigned short* __restrict__ A,
                                              const unsigned short* __restrict__ WT,
                                              const float* __restrict__ bias,
                                              const float* __restrict__ res,
                                              void* __restrict__ Cout,
                                              int ldc, int K) {
  constexpr int BN = 128;
  constexpr int BK = 64;                    // 128 B rows = 8 slots of 16 B
  constexpr int MF = BM / 32;               // per-wave m frags (4 or 2)
  constexpr int AJ = (BM * BK * 2 / 1024) / 4;  // A 1KB-chunk issues per thread
  constexpr int BJ = (BN * BK * 2 / 1024) / 4;  // B 1KB-chunk issues per thread
  __shared__ __align__(16) unsigned short As[2][BM][BK];
  __shared__ __align__(16) unsigned short Bs[2][BN][BK];
  const int tid = threadIdx.x;
  const int row0 = blockIdx.x * BM, col0 = blockIdx.y * BN;
  const int wave = tid >> 6, lane = tid & 63;
  const int wm = (wave >> 1) * (BM / 2), wn = (wave & 1) * 64;
  const int lr = lane & 15, lg = lane >> 4;
  // staging geometry: chunk = 1 KB = 8 rows; lane covers (row_in_chunk, slot)
  const int ric = lane >> 3;                // 0..7 row within chunk
  const int sslot = lane & 7;               // 0..7 16B slot

  auto stage = [&](int buf, int k0) {
    #pragma unroll
    for (int j = 0; j < AJ; ++j) {
      const int c = wave + 4 * j;
      const int row = c * 8 + ric;
      const int sp = sslot ^ (row & 7);     // inverse-swizzled source slot
      gload_lds16(A + (size_t)(row0 + row) * K + k0 + sp * 8,
                  (char*)&As[buf][0][0] + c * 1024);
    }
    #pragma unroll
    for (int j = 0; j < BJ; ++j) {
      const int c = wave + 4 * j;
      const int row = c * 8 + ric;
      const int sp = sslot ^ (row & 7);
      gload_lds16(WT + (size_t)(col0 + row) * K + k0 + sp * 8,
                  (char*)&Bs[buf][0][0] + c * 1024);
    }
  };

  f32x4 acc[MF][4] = {};
  const int nt = K / BK;
  stage(0, 0);
  __syncthreads();                          // vmcnt(0) drain: buf0 ready
  for (int t = 0; t < nt; ++t) {
    const int cur = t & 1;
    if (t + 1 < nt) stage(cur ^ 1, (t + 1) * BK);   // loads fly under MFMA
    #pragma unroll
    for (int ks = 0; ks < 2; ++ks) {
      bf16x8 af[MF], bfr[4];
      #pragma unroll
      for (int m = 0; m < MF; ++m) {
        const int r = wm + m * 16 + lr;
        const int s = (ks * 4 + lg) ^ (r & 7);
        af[m] = *(const bf16x8*)((const char*)&As[cur][0][0] + r * 128 + s * 16);
      }
      #pragma unroll
      for (int n = 0; n < 4; ++n) {
        const int r = wn + n * 16 + lr;
        const int s = (ks * 4 + lg) ^ (r & 7);
        bfr[n] = *(const bf16x8*)((const char*)&Bs[cur][0][0] + r * 128 + s * 16);
      }
      #pragma unroll
      for (int m = 0; m < MF; ++m)
        #pragma unroll
        for (int n = 0; n < 4; ++n)
          acc[m][n] = __builtin_amdgcn_mfma_f32_16x16x32_bf16(af[m], bfr[n], acc[m][n], 0, 0, 0);
    }
    __syncthreads();                        // next buffer staged, reads done
  }
  float* Cf = (float*)Cout;
  unsigned short* Cb = (unsigned short*)Cout;
  #pragma unroll
  for (int m = 0; m < MF; ++m) {
    #pragma unroll
    for (int n = 0; n < 4; ++n) {
      const int col = col0 + wn + (n << 4) + lr;
      const float bv = BIAS ? bias[col] : 0.0f;
      #pragma unroll
      for (int r = 0; r < 4; ++r) {
        const int row = row0 + wm + (m << 4) + (lg << 2) + r;
        float val = acc[m][n][r] + bv;
        if (RELU) val = fmaxf(val, 0.0f);
        if (RES)  val += res[(size_t)row * ldc + col];
        if (OBF16) Cb[(size_t)row * ldc + col] = f2bf(val);
        else       Cf[(size_t)row * ldc + col] = val;
      }
    }
  }
}

// ---------------- MFMA flash attention ------------------------------------
// qkv bf16 [2048][3072] (q|k|v), ob bf16 [2048][1024].
// Block = (q-tile 64 rows, head, batch); 4 waves, wave owns 16 q rows.
#define QBLK 64
#define KBLK 64
__global__ __launch_bounds__(256) void fattn_k(const unsigned short* __restrict__ qkv,
                                               unsigned short* __restrict__ ob) {
  const int qt = blockIdx.x, h = blockIdx.y, b = blockIdx.z;
  const int tid = threadIdx.x;
  const int wave = tid >> 6, lane = tid & 63;
  const int lr = lane & 15, lg = lane >> 4;      // lg = 0..3
  const int q0 = qt * QBLK;

  __shared__ __align__(16) unsigned short Qs[QBLK][72];
  __shared__ __align__(16) unsigned short Ks[KBLK][72];
  __shared__ __align__(16) unsigned short Vt[D_HEAD][72];   // transposed V
  __shared__ __align__(16) unsigned short Ps[QBLK][72];

  const size_t base = (size_t)b * T_SEQ * 3072 + (size_t)h * 64;
  const int srow = tid >> 3, scol = (tid & 7) << 3;

  // stage Q tile
  #pragma unroll
  for (int it = 0; it < 2; ++it) {
    const int row = srow + it * 32;
    *(uint4*)&Qs[row][scol] =
        *(const uint4*)(qkv + base + (size_t)(q0 + row) * 3072 + scol);
  }
  __syncthreads();
  bf16x8 qf[2];
  #pragma unroll
  for (int ks = 0; ks < 2; ++ks)
    qf[ks] = *(const bf16x8*)&Qs[wave * 16 + lr][ks * 32 + lg * 8];

  f32x4 acc_o[4] = {};
  float mrow[4], lrow[4];
  #pragma unroll
  for (int r = 0; r < 4; ++r) { mrow[r] = -3.0e38f; lrow[r] = 0.f; }

  const int ntile = qt + 1;
  for (int kt = 0; kt < ntile; ++kt) {
    const int s0 = kt * KBLK;
    __syncthreads();   // previous iteration done with Ks/Vt/Ps
    #pragma unroll
    for (int it = 0; it < 2; ++it) {
      const int row = srow + it * 32;
      *(uint4*)&Ks[row][scol] =
          *(const uint4*)(qkv + base + 1024 + (size_t)(s0 + row) * 3072 + scol);
      uint4 v4 = *(const uint4*)(qkv + base + 2048 + (size_t)(s0 + row) * 3072 + scol);
      const unsigned short* vs = (const unsigned short*)&v4;
      #pragma unroll
      for (int j = 0; j < 8; ++j) Vt[scol + j][row] = vs[j];
    }
    __syncthreads();

    // S = Q K^T (per wave: 16 q rows x 64 s cols)
    f32x4 sacc[4] = {};
    #pragma unroll
    for (int ks = 0; ks < 2; ++ks) {
      #pragma unroll
      for (int nf = 0; nf < 4; ++nf) {
        bf16x8 kf = *(const bf16x8*)&Ks[nf * 16 + lr][ks * 32 + lg * 8];
        sacc[nf] = __builtin_amdgcn_mfma_f32_16x16x32_bf16(qf[ks], kf, sacc[nf], 0, 0, 0);
      }
    }
    float sv[4][4];
    #pragma unroll
    for (int nf = 0; nf < 4; ++nf)
      #pragma unroll
      for (int r = 0; r < 4; ++r) sv[nf][r] = sacc[nf][r] * 0.125f;
    if (kt == ntile - 1) {         // diagonal tile: causal mask
      #pragma unroll
      for (int nf = 0; nf < 4; ++nf) {
        const int s = s0 + nf * 16 + lr;
        #pragma unroll
        for (int r = 0; r < 4; ++r) {
          const int q = q0 + wave * 16 + lg * 4 + r;
          if (s > q) sv[nf][r] = -3.0e38f;
        }
      }
    }
    // online softmax per q-row (rows live in 16-lane groups)
    float p[4][4];
    #pragma unroll
    for (int r = 0; r < 4; ++r) {
      float mx = fmaxf(fmaxf(sv[0][r], sv[1][r]), fmaxf(sv[2][r], sv[3][r]));
      #pragma unroll
      for (int off = 1; off < 16; off <<= 1) mx = fmaxf(mx, __shfl_xor(mx, off));
      const float mnew = fmaxf(mrow[r], mx);
      const float alpha = __expf(mrow[r] - mnew);
      mrow[r] = mnew;
      float sum = 0.f;
      #pragma unroll
      for (int nf = 0; nf < 4; ++nf) {
        p[nf][r] = __expf(sv[nf][r] - mnew);
        sum += p[nf][r];
      }
      #pragma unroll
      for (int off = 1; off < 16; off <<= 1) sum += __shfl_xor(sum, off);
      lrow[r] = lrow[r] * alpha + sum;
      #pragma unroll
      for (int df = 0; df < 4; ++df) acc_o[df][r] *= alpha;
    }
    // stage P (bf16) for the PV MFMA
    #pragma unroll
    for (int nf = 0; nf < 4; ++nf)
      #pragma unroll
      for (int r = 0; r < 4; ++r)
        Ps[wave * 16 + lg * 4 + r][nf * 16 + lr] = f2bf(p[nf][r]);
    __syncthreads();
    // O += P V
    #pragma unroll
    for (int ks = 0; ks < 2; ++ks) {
      bf16x8 pa = *(const bf16x8*)&Ps[wave * 16 + lr][ks * 32 + lg * 8];
      #pragma unroll
      for (int df = 0; df < 4; ++df) {
        bf16x8 vf = *(const bf16x8*)&Vt[df * 16 + lr][ks * 32 + lg * 8];
        acc_o[df] = __builtin_amdgcn_mfma_f32_16x16x32_bf16(pa, vf, acc_o[df], 0, 0, 0);
      }
    }
  }
  // epilogue: O / l -> ob
  #pragma unroll
  for (int r = 0; r < 4; ++r) {
    const float inv = 1.0f / lrow[r];
    const int row = q0 + wave * 16 + lg * 4 + r;
    #pragma unroll
    for (int df = 0; df < 4; ++df)
      ob[((size_t)b * T_SEQ + row) * E_DIM + h * 64 + df * 16 + lr] =
          f2bf(acc_o[df][r] * inv);
  }
}

extern "C" void kernel_launch(void* const* d_in, const int* in_sizes, int n_in,
                              void* d_out, int out_size, void* d_ws, size_t ws_size,
                              hipStream_t stream) {
  (void)in_sizes; (void)n_in; (void)out_size; (void)ws_size;
  const int*   idx    = (const int*)d_in[0];
  const float* tok_w  = (const float*)d_in[1];
  const float* pos    = (const float*)d_in[2];
  const float* ln1_s  = (const float*)d_in[3];
  const float* ln1_b  = (const float*)d_in[4];
  const float* wq     = (const float*)d_in[5];
  const float* wk     = (const float*)d_in[6];
  const float* wv     = (const float*)d_in[7];
  const float* wo     = (const float*)d_in[8];
  const float* bo     = (const float*)d_in[9];
  const float* ln2_s  = (const float*)d_in[10];
  const float* ln2_b  = (const float*)d_in[11];
  const float* w1     = (const float*)d_in[12];
  const float* b1     = (const float*)d_in[13];
  const float* w2     = (const float*)d_in[14];
  const float* b2     = (const float*)d_in[15];
  const float* lnf_s  = (const float*)d_in[16];
  const float* lnf_b  = (const float*)d_in[17];
  const float* head_w = (const float*)d_in[18];
  const float* head_b = (const float*)d_in[19];
  float* out = (float*)d_out;

  char* p = (char*)d_ws;
  float* x            = (float*)p;          p += (size_t)M_ROWS * E_DIM * 4;   // 8 MB
  unsigned short* qkvb= (unsigned short*)p; p += (size_t)M_ROWS * 3072 * 4;    // bf16 (slot 25 MB)
  unsigned short* h   = (unsigned short*)p; p += (size_t)M_ROWS * E_DIM * 2;   // 4 MB
  unsigned short* obuf= (unsigned short*)p; p += (size_t)M_ROWS * E_DIM * 2;   // 4 MB
  unsigned short* ff  = (unsigned short*)p; p += (size_t)M_ROWS * FF_DIM * 2;  // 16 MB
  unsigned short* wt  = (unsigned short*)p; p += (size_t)32000 * E_DIM * 2;    // 65.5 MB

  embed_k<<<M_ROWS, 256, 0, stream>>>(idx, tok_w, pos, x);

  for (int l = 0; l < L_NUM; ++l) {
    const size_t lEE = (size_t)l * E_DIM * E_DIM;
    const size_t lEF = (size_t)l * E_DIM * FF_DIM;
    // ---- LN1 ----
    ln_k<<<M_ROWS, 256, 0, stream>>>(x, ln1_s + l * E_DIM, ln1_b + l * E_DIM, h);
    // ---- QKV (fused, N = 3072, bf16 out) ----
    transpose_k<<<dim3(32, 32), 256, 0, stream>>>(wq + lEE, wt,               E_DIM, E_DIM);
    transpose_k<<<dim3(32, 32), 256, 0, stream>>>(wk + lEE, wt + 1048576,     E_DIM, E_DIM);
    transpose_k<<<dim3(32, 32), 256, 0, stream>>>(wv + lEE, wt + 2097152,     E_DIM, E_DIM);
    gemm_k<128,false,false,false,true><<<dim3(16, 24), 256, 0, stream>>>(
        h, wt, nullptr, nullptr, qkvb, 3072, E_DIM);
    // ---- flash attention ----
    fattn_k<<<dim3(T_SEQ / QBLK, H_NUM, B_NUM), 256, 0, stream>>>(qkvb, obuf);
    // ---- out-proj + bias + residual into x (BM=64) ----
    transpose_k<<<dim3(32, 32), 256, 0, stream>>>(wo + lEE, wt, E_DIM, E_DIM);
    gemm_k<64,false,true,true,false><<<dim3(32, 8), 256, 0, stream>>>(
        obuf, wt, bo + l * E_DIM, x, x, E_DIM, E_DIM);
    // ---- LN2 ----
    ln_k<<<M_ROWS, 256, 0, stream>>>(x, ln2_s + l * E_DIM, ln2_b + l * E_DIM, h);
    // ---- MLP up + ReLU (bf16 out) ----
    transpose_k<<<dim3(128, 32), 256, 0, stream>>>(w1 + lEF, wt, E_DIM, FF_DIM);
    gemm_k<128,true,true,false,true><<<dim3(16, 32), 256, 0, stream>>>(
        h, wt, b1 + l * FF_DIM, nullptr, ff, FF_DIM, E_DIM);
    // ---- MLP down + bias + residual into x (BM=64) ----
    transpose_k<<<dim3(32, 128), 256, 0, stream>>>(w2 + lEF, wt, FF_DIM, E_DIM);
    gemm_k<64,false,true,true,false><<<dim3(32, 8), 256, 0, stream>>>(
        ff, wt, b2 + l * E_DIM, x, x, E_DIM, FF_DIM);
  }

  // ---- final LN + head (single pass, N = 32000, m-fastest grid) ----
  ln_k<<<M_ROWS, 256, 0, stream>>>(x, lnf_s, lnf_b, h);
  transpose_k<<<dim3(1000, 32), 256, 0, stream>>>(head_w, wt, E_DIM, 32000);
  gemm_k<128,false,true,false,false><<<dim3(16, 250), 256, 0, stream>>>(
      h, wt, head_b, nullptr, out, 32000, E_DIM);
}